// Round 1
// baseline (401.218 us; speedup 1.0000x reference)
//
#include <hip/hip_runtime.h>

constexpr int B = 32, C = 64, N = 8192, R = 32, R3 = R * R * R;
constexpr int T = 1024;       // accum block size
constexpr int PPT = N / T;    // points per thread = 8 (register-cached)

// ---- workspace layout (needs ~6 MB) ---------------------------------------
constexpr size_t CNT_OFF = 0;                               // B*R3 u32 (4 MB)
constexpr size_t IDX_OFF = (size_t)B * R3 * 4;              // B*N u16 (512 KB)
constexpr size_t PF_OFF  = IDX_OFF + (size_t)B * N * 2;     // B*N f32 (1 MB)
constexpr size_t PRM_OFF = PF_OFF + (size_t)B * N * 4;      // B*4 f32

// ---------------------------------------------------------------------------
// K1: per-batch stats. Mean in f64; downstream replicates numpy f32 exactly
// (__f*_rn forbids FMA contraction; sum order matches np.linalg.norm).
// Also zeroes this batch's cnt slice (replaces the hipMemsetAsync dispatch;
// kernel-boundary ordering guarantees completion before voxelize's atomics).
// ---------------------------------------------------------------------------
__global__ __launch_bounds__(1024) void stats_kernel(
    const float* __restrict__ coords, float* __restrict__ params,
    unsigned int* __restrict__ cnt) {
  const int b = blockIdx.x;
  const int t = threadIdx.x;
  const float* cb = coords + (size_t)b * 3 * N;
  __shared__ double sm[1024];
  __shared__ float smf[1024];

  // zero cnt[b*R3 .. b*R3+R3) -- independent of the stats work below
  {
    uint4* cz = (uint4*)(cnt + (size_t)b * R3);
    const uint4 z4 = {0u, 0u, 0u, 0u};
#pragma unroll
    for (int k = 0; k < R3 / 4; k += 1024) cz[k + t] = z4;
  }

  double sx = 0.0, sy = 0.0, sz = 0.0;
  for (int n = t; n < N; n += 1024) {
    sx += (double)cb[n];
    sy += (double)cb[N + n];
    sz += (double)cb[2 * N + n];
  }
  float mean[3];
  double vals[3] = {sx, sy, sz};
  for (int d = 0; d < 3; ++d) {
    sm[t] = vals[d];
    __syncthreads();
    for (int s = 512; s > 0; s >>= 1) {
      if (t < s) sm[t] += sm[t + s];
      __syncthreads();
    }
    mean[d] = (float)(sm[0] / (double)N);
    __syncthreads();
  }

  float mx = 0.0f;
  for (int n = t; n < N; n += 1024) {
    float dx = __fsub_rn(cb[n], mean[0]);
    float dy = __fsub_rn(cb[N + n], mean[1]);
    float dz = __fsub_rn(cb[2 * N + n], mean[2]);
    float n2 = __fadd_rn(__fadd_rn(__fmul_rn(dx, dx), __fmul_rn(dy, dy)),
                         __fmul_rn(dz, dz));
    mx = fmaxf(mx, n2);
  }
  smf[t] = mx;
  __syncthreads();
  for (int s = 512; s > 0; s >>= 1) {
    if (t < s) smf[t] = fmaxf(smf[t], smf[t + s]);
    __syncthreads();
  }
  if (t == 0) {
    float maxn = __fsqrt_rn(smf[0]);
    params[b * 4 + 0] = mean[0];
    params[b * 4 + 1] = mean[1];
    params[b * 4 + 2] = mean[2];
    params[b * 4 + 3] = __fmul_rn(maxn, 2.0f);  // denominator (EPS == 0)
  }
}

// ---------------------------------------------------------------------------
// K2: per-point voxel id (u16, within-batch) + count atomic + norm_coords.
// ---------------------------------------------------------------------------
__global__ __launch_bounds__(256) void voxelize_kernel(
    const float* __restrict__ coords, const float* __restrict__ params,
    float* __restrict__ ncout, unsigned short* __restrict__ idx,
    unsigned int* __restrict__ cnt) {
  const int i = blockIdx.x * 256 + threadIdx.x;  // [0, B*N)
  const int b = i >> 13;                         // N = 8192
  const int n = i & (N - 1);
  const float* cb = coords + (size_t)b * 3 * N;
  const float m0 = params[b * 4 + 0];
  const float m1 = params[b * 4 + 1];
  const float m2 = params[b * 4 + 2];
  const float dn = params[b * 4 + 3];

  float t0 = __fmul_rn(__fadd_rn(__fdiv_rn(__fsub_rn(cb[n], m0), dn), 0.5f), 32.0f);
  float t1 = __fmul_rn(__fadd_rn(__fdiv_rn(__fsub_rn(cb[N + n], m1), dn), 0.5f), 32.0f);
  float t2 = __fmul_rn(__fadd_rn(__fdiv_rn(__fsub_rn(cb[2 * N + n], m2), dn), 0.5f), 32.0f);
  t0 = fminf(fmaxf(t0, 0.0f), 31.0f);
  t1 = fminf(fmaxf(t1, 0.0f), 31.0f);
  t2 = fminf(fmaxf(t2, 0.0f), 31.0f);

  ncout[(size_t)b * 3 * N + n] = t0;
  ncout[(size_t)b * 3 * N + N + n] = t1;
  ncout[(size_t)b * 3 * N + 2 * N + n] = t2;

  const int vx = (int)rintf(t0);  // half-to-even == np.round
  const int vy = (int)rintf(t1);
  const int vz = (int)rintf(t2);
  const int flat = (vx * R + vy) * R + vz;  // [0, 32768)
  idx[i] = (unsigned short)flat;
  atomicAdd(&cnt[b * R3 + flat], 1u);
}

// ---------------------------------------------------------------------------
// K2.5: per-point reciprocal count. pf[i] = 1/max(cnt[voxel(i)],1).
// cnt gathers are L2-resident (4 MB region, just written). Moves the divide
// off accum's store path so accum never touches cnt: avg = sum(f * 1/c).
// ---------------------------------------------------------------------------
__global__ __launch_bounds__(256) void invp_kernel(
    const unsigned short* __restrict__ idx,
    const unsigned int* __restrict__ cnt, float* __restrict__ pf) {
  const int i = blockIdx.x * 256 + threadIdx.x;  // [0, B*N)
  const int b = i >> 13;
  const unsigned int k = cnt[b * R3 + (int)idx[i]];
  pf[i] = __fdiv_rn(1.0f, (float)(k ? k : 1u));
}

// ---------------------------------------------------------------------------
// K3: one block per (b,c). SINGLE-PASS full-grid version: the whole R^3 slab
// (128 KB) lives in LDS (gfx950 allows up to 160 KB/workgroup), so:
//   - 8 unpredicated ds-atomics per thread (vs 16 predicated in the old
//     two-pass half-grid scheme -- no exec-mask churn, half the issue),
//   - no mid-kernel vmcnt(0)+barrier store drains (the old post-dump
//     __syncthreads forced a full 64 KB drain twice per block),
//   - no __launch_bounds__ VGPR cap: 128 KB LDS forces 1 block/CU anyway,
//     so the old 64-VGPR crunch (spill risk) bought nothing.
// Point loads are issued BEFORE the zero loop so their HBM latency hides
// under 128 KB of LDS zeroing. Kernel-end store drain overlaps the next
// block's zero phase (LDS handoff only needs ds-reads complete).
// ---------------------------------------------------------------------------
__global__ __launch_bounds__(1024) void accum_kernel(
    const float* __restrict__ feats, const unsigned short* __restrict__ idx,
    const float* __restrict__ pf, float* __restrict__ voxout) {
  __shared__ float lds[R3];  // 128 KB
  const int blk = blockIdx.x;  // b*C + c
  const int c = blk & (C - 1);
  const int b = blk >> 6;
  const int t = threadIdx.x;

  const unsigned short* ib = idx + (size_t)b * N;
  const float* pb = pf + (size_t)b * N;
  const float* fb = feats + ((size_t)b * C + c) * N;

  // issue all point loads first (coalesced); waits land after the zero loop
  int iv[PPT];
  float fv[PPT];
#pragma unroll
  for (int k = 0; k < PPT; ++k) {
    const int n = t + k * T;
    iv[k] = (int)ib[n];
    fv[k] = fb[n] * pb[n];
  }

  // zero the full grid (hides the global-load latency above)
  float4* lp = (float4*)lds;
  const float4 z = {0.f, 0.f, 0.f, 0.f};
#pragma unroll
  for (int k = 0; k < R3 / 4; k += T) lp[k + t] = z;
  __syncthreads();

  // scatter from registers (ds_add_f32; unpredicated, no global traffic)
#pragma unroll
  for (int k = 0; k < PPT; ++k) atomicAdd(&lds[iv[k]], fv[k]);
  __syncthreads();

  // plain coalesced dump of the exclusive 128 KB slice; no trailing barrier
  float4* ob4 = (float4*)(voxout + ((size_t)b * C + c) * R3);
#pragma unroll
  for (int v = 0; v < R3 / 4; v += T) ob4[v + t] = lp[v + t];
}

extern "C" void kernel_launch(void* const* d_in, const int* in_sizes, int n_in,
                              void* d_out, int out_size, void* d_ws,
                              size_t ws_size, hipStream_t stream) {
  const float* feats  = (const float*)d_in[0];  // [B, C, N]
  const float* coords = (const float*)d_in[1];  // [B, 3, N]

  float* voxout = (float*)d_out;                // [B, C, R,R,R]
  float* ncout  = voxout + (size_t)B * C * R3;  // [B, 3, N]

  char* ws = (char*)d_ws;
  unsigned int* cnt   = (unsigned int*)(ws + CNT_OFF);
  unsigned short* idx = (unsigned short*)(ws + IDX_OFF);
  float* pf           = (float*)(ws + PF_OFF);
  float* params       = (float*)(ws + PRM_OFF);

  stats_kernel<<<B, 1024, 0, stream>>>(coords, params, cnt);
  voxelize_kernel<<<(B * N) / 256, 256, 0, stream>>>(coords, params, ncout,
                                                     idx, cnt);
  invp_kernel<<<(B * N) / 256, 256, 0, stream>>>(idx, cnt, pf);
  accum_kernel<<<B * C, 1024, 0, stream>>>(feats, idx, pf, voxout);
}

// Round 2
// 377.981 us; speedup vs baseline: 1.0615x; 1.0615x over previous
//
#include <hip/hip_runtime.h>

constexpr int B = 32, C = 64, N = 8192, R = 32, R3 = R * R * R;
constexpr int HALF = R3 / 2;  // 16384 voxels -> 64 KB LDS slab
constexpr int T = 1024;       // accum block size
constexpr int PPT = N / T;    // points per thread = 8 (register-cached)

// ---- workspace layout (needs ~6 MB) ---------------------------------------
constexpr size_t CNT_OFF = 0;                               // B*R3 u32 (4 MB)
constexpr size_t IDX_OFF = (size_t)B * R3 * 4;              // B*N u16 (512 KB)
constexpr size_t PF_OFF  = IDX_OFF + (size_t)B * N * 2;     // B*N f32 (1 MB)
constexpr size_t PRM_OFF = PF_OFF + (size_t)B * N * 4;      // B*4 f32

// LDS-only barrier: the accum pass boundaries guard ONLY LDS hazards (slab
// zero/scatter/read). __syncthreads() would emit s_waitcnt vmcnt(0) before
// s_barrier, draining the 64 KB global dump stores at every pass boundary.
// lgkmcnt(0) alone guarantees each wave's ds writes/atomics/reads are
// complete before the barrier; global stores (exclusive output slice, never
// read in-kernel) stay in flight under the next pass's LDS work.
__device__ __forceinline__ void lds_barrier() {
  asm volatile("s_waitcnt lgkmcnt(0)" ::: "memory");
  __builtin_amdgcn_s_barrier();
  __builtin_amdgcn_sched_barrier(0);
}

// ---------------------------------------------------------------------------
// K1: per-batch stats. Mean in f64; downstream replicates numpy f32 exactly
// (__f*_rn forbids FMA contraction; sum order matches np.linalg.norm).
// Also zeroes this batch's cnt slice (replaces the hipMemsetAsync dispatch;
// kernel-boundary ordering guarantees completion before voxelize's atomics).
// ---------------------------------------------------------------------------
__global__ __launch_bounds__(1024) void stats_kernel(
    const float* __restrict__ coords, float* __restrict__ params,
    unsigned int* __restrict__ cnt) {
  const int b = blockIdx.x;
  const int t = threadIdx.x;
  const float* cb = coords + (size_t)b * 3 * N;
  __shared__ double sm[1024];
  __shared__ float smf[1024];

  // zero cnt[b*R3 .. b*R3+R3) -- independent of the stats work below
  {
    uint4* cz = (uint4*)(cnt + (size_t)b * R3);
    const uint4 z4 = {0u, 0u, 0u, 0u};
#pragma unroll
    for (int k = 0; k < R3 / 4; k += 1024) cz[k + t] = z4;
  }

  double sx = 0.0, sy = 0.0, sz = 0.0;
  for (int n = t; n < N; n += 1024) {
    sx += (double)cb[n];
    sy += (double)cb[N + n];
    sz += (double)cb[2 * N + n];
  }
  float mean[3];
  double vals[3] = {sx, sy, sz};
  for (int d = 0; d < 3; ++d) {
    sm[t] = vals[d];
    __syncthreads();
    for (int s = 512; s > 0; s >>= 1) {
      if (t < s) sm[t] += sm[t + s];
      __syncthreads();
    }
    mean[d] = (float)(sm[0] / (double)N);
    __syncthreads();
  }

  float mx = 0.0f;
  for (int n = t; n < N; n += 1024) {
    float dx = __fsub_rn(cb[n], mean[0]);
    float dy = __fsub_rn(cb[N + n], mean[1]);
    float dz = __fsub_rn(cb[2 * N + n], mean[2]);
    float n2 = __fadd_rn(__fadd_rn(__fmul_rn(dx, dx), __fmul_rn(dy, dy)),
                         __fmul_rn(dz, dz));
    mx = fmaxf(mx, n2);
  }
  smf[t] = mx;
  __syncthreads();
  for (int s = 512; s > 0; s >>= 1) {
    if (t < s) smf[t] = fmaxf(smf[t], smf[t + s]);
    __syncthreads();
  }
  if (t == 0) {
    float maxn = __fsqrt_rn(smf[0]);
    params[b * 4 + 0] = mean[0];
    params[b * 4 + 1] = mean[1];
    params[b * 4 + 2] = mean[2];
    params[b * 4 + 3] = __fmul_rn(maxn, 2.0f);  // denominator (EPS == 0)
  }
}

// ---------------------------------------------------------------------------
// K2: per-point voxel id (u16, within-batch) + count atomic + norm_coords.
// ---------------------------------------------------------------------------
__global__ __launch_bounds__(256) void voxelize_kernel(
    const float* __restrict__ coords, const float* __restrict__ params,
    float* __restrict__ ncout, unsigned short* __restrict__ idx,
    unsigned int* __restrict__ cnt) {
  const int i = blockIdx.x * 256 + threadIdx.x;  // [0, B*N)
  const int b = i >> 13;                         // N = 8192
  const int n = i & (N - 1);
  const float* cb = coords + (size_t)b * 3 * N;
  const float m0 = params[b * 4 + 0];
  const float m1 = params[b * 4 + 1];
  const float m2 = params[b * 4 + 2];
  const float dn = params[b * 4 + 3];

  float t0 = __fmul_rn(__fadd_rn(__fdiv_rn(__fsub_rn(cb[n], m0), dn), 0.5f), 32.0f);
  float t1 = __fmul_rn(__fadd_rn(__fdiv_rn(__fsub_rn(cb[N + n], m1), dn), 0.5f), 32.0f);
  float t2 = __fmul_rn(__fadd_rn(__fdiv_rn(__fsub_rn(cb[2 * N + n], m2), dn), 0.5f), 32.0f);
  t0 = fminf(fmaxf(t0, 0.0f), 31.0f);
  t1 = fminf(fmaxf(t1, 0.0f), 31.0f);
  t2 = fminf(fmaxf(t2, 0.0f), 31.0f);

  ncout[(size_t)b * 3 * N + n] = t0;
  ncout[(size_t)b * 3 * N + N + n] = t1;
  ncout[(size_t)b * 3 * N + 2 * N + n] = t2;

  const int vx = (int)rintf(t0);  // half-to-even == np.round
  const int vy = (int)rintf(t1);
  const int vz = (int)rintf(t2);
  const int flat = (vx * R + vy) * R + vz;  // [0, 32768)
  idx[i] = (unsigned short)flat;
  atomicAdd(&cnt[b * R3 + flat], 1u);
}

// ---------------------------------------------------------------------------
// K2.5: per-point reciprocal count. pf[i] = 1/max(cnt[voxel(i)],1).
// cnt gathers are L2-resident (4 MB region, just written). Moves the divide
// off accum's store path so accum never touches cnt: avg = sum(f * 1/c).
// ---------------------------------------------------------------------------
__global__ __launch_bounds__(256) void invp_kernel(
    const unsigned short* __restrict__ idx,
    const unsigned int* __restrict__ cnt, float* __restrict__ pf) {
  const int i = blockIdx.x * 256 + threadIdx.x;  // [0, B*N)
  const int b = i >> 13;
  const unsigned int k = cnt[b * R3 + (int)idx[i]];
  pf[i] = __fdiv_rn(1.0f, (float)(k ? k : 1u));
}

// ---------------------------------------------------------------------------
// K3: one block per (b,c). Two-pass half-grid (64 KB slab): LDS caps
// residency at 2 blocks/CU; __launch_bounds__(1024,8) caps VGPR at 64 so
// 32 waves actually fit (this co-residency is what hides per-block phase
// exposure -- round-1's 128 KB single-pass variant lost 23 µs to it).
// Pass boundaries use lds_barrier() (lgkm-only): the slab hazards are pure
// LDS, so the 64 KB global dump stores are NOT drained at each boundary --
// they stay in flight under the next pass's zero+scatter (removes the
// vmcnt(0)-before-s_barrier stall __syncthreads would force, 2x per block).
// ---------------------------------------------------------------------------
__global__ __launch_bounds__(1024, 8) void accum_kernel(
    const float* __restrict__ feats, const unsigned short* __restrict__ idx,
    const float* __restrict__ pf, float* __restrict__ voxout) {
  __shared__ float lds[HALF];
  const int blk = blockIdx.x;  // b*C + c
  const int c = blk & (C - 1);
  const int b = blk >> 6;
  const int t = threadIdx.x;

  // register-cache this thread's points (coalesced loads, done once);
  // feature pre-scaled by its voxel's 1/cnt.
  const unsigned short* ib = idx + (size_t)b * N;
  const float* pb = pf + (size_t)b * N;
  const float* fb = feats + ((size_t)b * C + c) * N;
  int iv[PPT];
  float fv[PPT];
#pragma unroll
  for (int k = 0; k < PPT; ++k) {
    const int n = t + k * T;
    iv[k] = (int)ib[n];
    fv[k] = fb[n] * pb[n];
  }

  float4* lp = (float4*)lds;
  const float4 z = {0.f, 0.f, 0.f, 0.f};

  for (int h = 0; h < 2; ++h) {
    const int lo = h * HALF;

    // zero the slab (first pass: overlaps the in-flight point loads above)
#pragma unroll
    for (int k = t; k < HALF / 4; k += T) lp[k] = z;
    lds_barrier();

    // scatter from registers (ds_add_f32; no global traffic)
#pragma unroll
    for (int k = 0; k < PPT; ++k) {
      const int loc = iv[k] - lo;
      if ((unsigned)loc < (unsigned)HALF) atomicAdd(&lds[loc], fv[k]);
    }
    lds_barrier();

    // plain coalesced dump of the exclusive 64 KB slice; stores are left
    // in flight across the next barrier (exclusive region, lgkm-only sync)
    float4* ob4 = (float4*)(voxout + ((size_t)b * C + c) * R3 + lo);
#pragma unroll
    for (int v = t; v < HALF / 4; v += T) ob4[v] = lp[v];
    if (h == 0) lds_barrier();  // slab reused next pass
  }
}

extern "C" void kernel_launch(void* const* d_in, const int* in_sizes, int n_in,
                              void* d_out, int out_size, void* d_ws,
                              size_t ws_size, hipStream_t stream) {
  const float* feats  = (const float*)d_in[0];  // [B, C, N]
  const float* coords = (const float*)d_in[1];  // [B, 3, N]

  float* voxout = (float*)d_out;                // [B, C, R,R,R]
  float* ncout  = voxout + (size_t)B * C * R3;  // [B, 3, N]

  char* ws = (char*)d_ws;
  unsigned int* cnt   = (unsigned int*)(ws + CNT_OFF);
  unsigned short* idx = (unsigned short*)(ws + IDX_OFF);
  float* pf           = (float*)(ws + PF_OFF);
  float* params       = (float*)(ws + PRM_OFF);

  stats_kernel<<<B, 1024, 0, stream>>>(coords, params, cnt);
  voxelize_kernel<<<(B * N) / 256, 256, 0, stream>>>(coords, params, ncout,
                                                     idx, cnt);
  invp_kernel<<<(B * N) / 256, 256, 0, stream>>>(idx, cnt, pf);
  accum_kernel<<<B * C, 1024, 0, stream>>>(feats, idx, pf, voxout);
}

// Round 4
// 368.755 us; speedup vs baseline: 1.0880x; 1.0250x over previous
//
#include <hip/hip_runtime.h>

constexpr int B = 32, C = 64, N = 8192, R = 32, R3 = R * R * R;
constexpr int HALF = R3 / 2;  // 16384 voxels -> 64 KB LDS slab (accum)
constexpr int T = 1024;       // block size
constexpr int PPT = N / T;    // points per thread = 8

// ---- workspace layout (~1.5 MB) -------------------------------------------
constexpr size_t IDX_OFF = 0;                            // B*N u16 (512 KB)
constexpr size_t PF_OFF  = (size_t)B * N * 2;            // B*N f32 (1 MB)

// LDS-only barrier: guards LDS hazards without the vmcnt(0) drain that
// __syncthreads() forces -- global stores (ncout/idx/voxout, exclusive
// regions never read in-kernel) stay in flight across it.
__device__ __forceinline__ void lds_barrier() {
  asm volatile("s_waitcnt lgkmcnt(0)" ::: "memory");
  __builtin_amdgcn_s_barrier();
  __builtin_amdgcn_sched_barrier(0);
}

// ---------------------------------------------------------------------------
// K1: fused per-batch prep. One block per batch owns everything:
//   1. stats: mean in f64 (bit-identical tree to prior rounds), max-norm in
//      f32 (__f*_rn forbids FMA contraction; order matches np.linalg.norm).
//      Result stays in registers -- no params round trip.
//   2. count: the batch's full 32^3 count grid lives in LDS (128 KB, proven
//      on gfx950 in round 1). Zero it, then per-point LDS atomicAdd.
//      Replaces: global cnt memset (4 MB), 262K global atomics, and the
//      separate voxelize + invp dispatches (+2 kernel boundaries).
//   3. emit: ncout, idx (u16), and per-point pf = 1/cnt straight from LDS.
//      A point's own voxel has cnt >= 1, so no max(cnt,1) needed.
// The reduction scratch aliases the count slab (phases are barriered), so
// total LDS stays exactly 128 KB.
// ---------------------------------------------------------------------------
__global__ __launch_bounds__(1024) void prep_kernel(
    const float* __restrict__ coords, float* __restrict__ ncout,
    unsigned short* __restrict__ idx, float* __restrict__ pf) {
  __shared__ __align__(16) unsigned char smem[R3 * 4];  // 128 KB
  double* sm = (double*)smem;              // [1024] during mean phase
  float* smf = (float*)smem;               // [1024] during max phase
  unsigned int* cnt = (unsigned int*)smem; // [R3] during count phase

  const int b = blockIdx.x;
  const int t = threadIdx.x;
  const float* cb = coords + (size_t)b * 3 * N;

  // ---- mean (f64, identical reduction order to prior rounds) ----
  double sx = 0.0, sy = 0.0, sz = 0.0;
  for (int n = t; n < N; n += T) {
    sx += (double)cb[n];
    sy += (double)cb[N + n];
    sz += (double)cb[2 * N + n];
  }
  float mean[3];
  double vals[3] = {sx, sy, sz};
  for (int d = 0; d < 3; ++d) {
    sm[t] = vals[d];
    __syncthreads();
    for (int s = 512; s > 0; s >>= 1) {
      if (t < s) sm[t] += sm[t + s];
      __syncthreads();
    }
    mean[d] = (float)(sm[0] / (double)N);
    __syncthreads();
  }

  // ---- max point norm (f32, order matches np.linalg.norm) ----
  float mx = 0.0f;
  for (int n = t; n < N; n += T) {
    float dx = __fsub_rn(cb[n], mean[0]);
    float dy = __fsub_rn(cb[N + n], mean[1]);
    float dz = __fsub_rn(cb[2 * N + n], mean[2]);
    float n2 = __fadd_rn(__fadd_rn(__fmul_rn(dx, dx), __fmul_rn(dy, dy)),
                         __fmul_rn(dz, dz));
    mx = fmaxf(mx, n2);
  }
  smf[t] = mx;
  __syncthreads();
  for (int s = 512; s > 0; s >>= 1) {
    if (t < s) smf[t] = fmaxf(smf[t], smf[t + s]);
    __syncthreads();
  }
  const float dn = __fmul_rn(__fsqrt_rn(smf[0]), 2.0f);  // EPS == 0
  __syncthreads();  // everyone has read smf[0]; slab may now be reused

  // ---- zero the LDS count grid ----
  {
    uint4* cz = (uint4*)cnt;
    const uint4 z4 = {0u, 0u, 0u, 0u};
#pragma unroll
    for (int k = 0; k < R3 / 4; k += T) cz[k + t] = z4;
  }
  lds_barrier();

  // ---- voxelize: ncout + idx writes, LDS count atomics ----
  int iv[PPT];
#pragma unroll
  for (int k = 0; k < PPT; ++k) {
    const int n = t + k * T;
    float t0 = __fmul_rn(__fadd_rn(__fdiv_rn(__fsub_rn(cb[n], mean[0]), dn), 0.5f), 32.0f);
    float t1 = __fmul_rn(__fadd_rn(__fdiv_rn(__fsub_rn(cb[N + n], mean[1]), dn), 0.5f), 32.0f);
    float t2 = __fmul_rn(__fadd_rn(__fdiv_rn(__fsub_rn(cb[2 * N + n], mean[2]), dn), 0.5f), 32.0f);
    t0 = fminf(fmaxf(t0, 0.0f), 31.0f);
    t1 = fminf(fmaxf(t1, 0.0f), 31.0f);
    t2 = fminf(fmaxf(t2, 0.0f), 31.0f);

    ncout[(size_t)b * 3 * N + n] = t0;
    ncout[(size_t)b * 3 * N + N + n] = t1;
    ncout[(size_t)b * 3 * N + 2 * N + n] = t2;

    const int vx = (int)rintf(t0);  // half-to-even == np.round
    const int vy = (int)rintf(t1);
    const int vz = (int)rintf(t2);
    const int flat = (vx * R + vy) * R + vz;  // [0, 32768)
    iv[k] = flat;
    idx[(size_t)b * N + n] = (unsigned short)flat;
    atomicAdd(&cnt[flat], 1u);
  }
  lds_barrier();  // atomics complete; ncout/idx stores stay in flight

  // ---- per-point reciprocal count from LDS ----
#pragma unroll
  for (int k = 0; k < PPT; ++k) {
    const int n = t + k * T;
    pf[(size_t)b * N + n] = __fdiv_rn(1.0f, (float)cnt[iv[k]]);
  }
}

// ---------------------------------------------------------------------------
// K2: one block per (b,c). Two-pass half-grid (64 KB slab): LDS caps
// residency at 2 blocks/CU; __launch_bounds__(1024,8) caps VGPR at 64 so
// 32 waves actually fit (round-1's 128 KB single-pass variant lost 23 µs
// to losing this co-residency). lgkm-only barriers leave the 64 KB dump
// stores in flight under the next pass's zero+scatter.
// ---------------------------------------------------------------------------
__global__ __launch_bounds__(1024, 8) void accum_kernel(
    const float* __restrict__ feats, const unsigned short* __restrict__ idx,
    const float* __restrict__ pf, float* __restrict__ voxout) {
  __shared__ float lds[HALF];
  const int blk = blockIdx.x;  // b*C + c
  const int c = blk & (C - 1);
  const int b = blk >> 6;
  const int t = threadIdx.x;

  // register-cache this thread's points (coalesced loads, done once);
  // feature pre-scaled by its voxel's 1/cnt.
  const unsigned short* ib = idx + (size_t)b * N;
  const float* pb = pf + (size_t)b * N;
  const float* fb = feats + ((size_t)b * C + c) * N;
  int iv[PPT];
  float fv[PPT];
#pragma unroll
  for (int k = 0; k < PPT; ++k) {
    const int n = t + k * T;
    iv[k] = (int)ib[n];
    fv[k] = fb[n] * pb[n];
  }

  float4* lp = (float4*)lds;
  const float4 z = {0.f, 0.f, 0.f, 0.f};

  for (int h = 0; h < 2; ++h) {
    const int lo = h * HALF;

    // zero the slab (first pass: overlaps the in-flight point loads above)
#pragma unroll
    for (int k = t; k < HALF / 4; k += T) lp[k] = z;
    lds_barrier();

    // scatter from registers (ds_add_f32; no global traffic)
#pragma unroll
    for (int k = 0; k < PPT; ++k) {
      const int loc = iv[k] - lo;
      if ((unsigned)loc < (unsigned)HALF) atomicAdd(&lds[loc], fv[k]);
    }
    lds_barrier();

    // plain coalesced dump of the exclusive 64 KB slice; stores left in
    // flight across the next barrier (exclusive region, lgkm-only sync)
    float4* ob4 = (float4*)(voxout + ((size_t)b * C + c) * R3 + lo);
#pragma unroll
    for (int v = t; v < HALF / 4; v += T) ob4[v] = lp[v];
    if (h == 0) lds_barrier();  // slab reused next pass
  }
}

extern "C" void kernel_launch(void* const* d_in, const int* in_sizes, int n_in,
                              void* d_out, int out_size, void* d_ws,
                              size_t ws_size, hipStream_t stream) {
  const float* feats  = (const float*)d_in[0];  // [B, C, N]
  const float* coords = (const float*)d_in[1];  // [B, 3, N]

  float* voxout = (float*)d_out;                // [B, C, R,R,R]
  float* ncout  = voxout + (size_t)B * C * R3;  // [B, 3, N]

  char* ws = (char*)d_ws;
  unsigned short* idx = (unsigned short*)(ws + IDX_OFF);
  float* pf           = (float*)(ws + PF_OFF);

  prep_kernel<<<B, 1024, 0, stream>>>(coords, ncout, idx, pf);
  accum_kernel<<<B * C, 1024, 0, stream>>>(feats, idx, pf, voxout);
}

// Round 5
// 366.674 us; speedup vs baseline: 1.0942x; 1.0057x over previous
//
#include <hip/hip_runtime.h>

constexpr int B = 32, C = 64, N = 8192, R = 32, R3 = R * R * R;
constexpr int HALF = R3 / 2;  // 16384 voxels -> 64 KB LDS slab (accum)
constexpr int T = 1024;       // block size
constexpr int PPT = N / T;    // points per thread = 8

// native clang vectors (HIP's float4 is a struct; nontemporal builtins need
// true vector types)
typedef float f32x4 __attribute__((ext_vector_type(4)));
typedef unsigned int u32x4 __attribute__((ext_vector_type(4)));

// ---- workspace layout (~1.5 MB) -------------------------------------------
constexpr size_t IDX_OFF = 0;                            // B*N u16 (512 KB)
constexpr size_t PF_OFF  = (size_t)B * N * 2;            // B*N f32 (1 MB)

// LDS-only barrier: guards LDS hazards without the vmcnt(0) drain that
// __syncthreads() forces -- global stores (ncout/idx/voxout, exclusive
// regions never read in-kernel) stay in flight across it.
__device__ __forceinline__ void lds_barrier() {
  asm volatile("s_waitcnt lgkmcnt(0)" ::: "memory");
  __builtin_amdgcn_s_barrier();
  __builtin_amdgcn_sched_barrier(0);
}

// ---------------------------------------------------------------------------
// K1: fused per-batch prep (one block per batch).
//   1. stats: mean in f64 (loop + tree untouched -- bit-identical), max-norm
//      f32 (fmax is associative; loop untouched anyway).
//   2. count grid in 128 KB LDS; zero + per-point LDS atomics.
//   3. emit ncout/idx/pf with per-thread-contiguous points (n = t*8+k):
//      vectorized f32x4/u32x4 access, 6 loads + 9 stores per thread instead
//      of 24 + 27 scalars. Point->thread assignment is arbitrary for these
//      phases (per-point math unchanged), so outputs are bit-identical.
//      ncout uses nontemporal stores (pure output, never re-read).
// ---------------------------------------------------------------------------
__global__ __launch_bounds__(1024) void prep_kernel(
    const float* __restrict__ coords, float* __restrict__ ncout,
    unsigned short* __restrict__ idx, float* __restrict__ pf) {
  __shared__ __align__(16) unsigned char smem[R3 * 4];  // 128 KB
  double* sm = (double*)smem;              // [1024] during mean phase
  float* smf = (float*)smem;               // [1024] during max phase
  unsigned int* cnt = (unsigned int*)smem; // [R3] during count phase

  const int b = blockIdx.x;
  const int t = threadIdx.x;
  const float* cb = coords + (size_t)b * 3 * N;

  // ---- mean (f64, identical reduction order to prior rounds) ----
  double sx = 0.0, sy = 0.0, sz = 0.0;
  for (int n = t; n < N; n += T) {
    sx += (double)cb[n];
    sy += (double)cb[N + n];
    sz += (double)cb[2 * N + n];
  }
  float mean[3];
  double vals[3] = {sx, sy, sz};
  for (int d = 0; d < 3; ++d) {
    sm[t] = vals[d];
    __syncthreads();
    for (int s = 512; s > 0; s >>= 1) {
      if (t < s) sm[t] += sm[t + s];
      __syncthreads();
    }
    mean[d] = (float)(sm[0] / (double)N);
    __syncthreads();
  }

  // ---- max point norm (f32; fmax associative, order-free) ----
  float mx = 0.0f;
  for (int n = t; n < N; n += T) {
    float dx = __fsub_rn(cb[n], mean[0]);
    float dy = __fsub_rn(cb[N + n], mean[1]);
    float dz = __fsub_rn(cb[2 * N + n], mean[2]);
    float n2 = __fadd_rn(__fadd_rn(__fmul_rn(dx, dx), __fmul_rn(dy, dy)),
                         __fmul_rn(dz, dz));
    mx = fmaxf(mx, n2);
  }
  smf[t] = mx;
  __syncthreads();
  for (int s = 512; s > 0; s >>= 1) {
    if (t < s) smf[t] = fmaxf(smf[t], smf[t + s]);
    __syncthreads();
  }
  const float dn = __fmul_rn(__fsqrt_rn(smf[0]), 2.0f);  // EPS == 0
  __syncthreads();  // everyone has read smf[0]; slab may now be reused

  // issue this thread's coord vector loads early (independent of LDS work;
  // L2-hot after the stats passes). n0 = t*8: thread-contiguous points.
  const int n0 = t * PPT;
  const f32x4 xa = *(const f32x4*)(cb + n0);
  const f32x4 xc = *(const f32x4*)(cb + n0 + 4);
  const f32x4 ya = *(const f32x4*)(cb + N + n0);
  const f32x4 yc = *(const f32x4*)(cb + N + n0 + 4);
  const f32x4 za = *(const f32x4*)(cb + 2 * N + n0);
  const f32x4 zc = *(const f32x4*)(cb + 2 * N + n0 + 4);

  // ---- zero the LDS count grid ----
  {
    u32x4* cz = (u32x4*)cnt;
    const u32x4 z4 = {0u, 0u, 0u, 0u};
#pragma unroll
    for (int k = 0; k < R3 / 4; k += T) cz[k + t] = z4;
  }
  lds_barrier();

  // ---- voxelize: per-point math identical to prior rounds ----
  int iv[PPT];
  f32x4 o0[2], o1[2], o2[2];
#pragma unroll
  for (int h = 0; h < 2; ++h) {
    const f32x4 xs = h ? xc : xa;
    const f32x4 ys = h ? yc : ya;
    const f32x4 zs = h ? zc : za;
#pragma unroll
    for (int j = 0; j < 4; ++j) {
      float t0 = __fmul_rn(__fadd_rn(__fdiv_rn(__fsub_rn(xs[j], mean[0]), dn), 0.5f), 32.0f);
      float t1 = __fmul_rn(__fadd_rn(__fdiv_rn(__fsub_rn(ys[j], mean[1]), dn), 0.5f), 32.0f);
      float t2 = __fmul_rn(__fadd_rn(__fdiv_rn(__fsub_rn(zs[j], mean[2]), dn), 0.5f), 32.0f);
      t0 = fminf(fmaxf(t0, 0.0f), 31.0f);
      t1 = fminf(fmaxf(t1, 0.0f), 31.0f);
      t2 = fminf(fmaxf(t2, 0.0f), 31.0f);
      o0[h][j] = t0;
      o1[h][j] = t1;
      o2[h][j] = t2;
      const int vx = (int)rintf(t0);  // half-to-even == np.round
      const int vy = (int)rintf(t1);
      const int vz = (int)rintf(t2);
      iv[h * 4 + j] = (vx * R + vy) * R + vz;  // [0, 32768)
    }
  }

  // ncout: pure output -> nontemporal vector stores
  float* nc = ncout + (size_t)b * 3 * N;
  __builtin_nontemporal_store(o0[0], (f32x4*)(nc + n0));
  __builtin_nontemporal_store(o0[1], (f32x4*)(nc + n0 + 4));
  __builtin_nontemporal_store(o1[0], (f32x4*)(nc + N + n0));
  __builtin_nontemporal_store(o1[1], (f32x4*)(nc + N + n0 + 4));
  __builtin_nontemporal_store(o2[0], (f32x4*)(nc + 2 * N + n0));
  __builtin_nontemporal_store(o2[1], (f32x4*)(nc + 2 * N + n0 + 4));

  // idx: packed u16x8 = one 16 B store (re-read by accum -> cached store)
  {
    u32x4 iw = {(unsigned)iv[0] | ((unsigned)iv[1] << 16),
                (unsigned)iv[2] | ((unsigned)iv[3] << 16),
                (unsigned)iv[4] | ((unsigned)iv[5] << 16),
                (unsigned)iv[6] | ((unsigned)iv[7] << 16)};
    *(u32x4*)(idx + (size_t)b * N + n0) = iw;
  }

  // count atomics
#pragma unroll
  for (int k = 0; k < PPT; ++k) atomicAdd(&cnt[iv[k]], 1u);
  lds_barrier();  // atomics complete; global stores stay in flight

  // ---- per-point reciprocal count from LDS (cached stores) ----
  f32x4 q0, q1;
#pragma unroll
  for (int j = 0; j < 4; ++j) {
    q0[j] = __fdiv_rn(1.0f, (float)cnt[iv[j]]);
    q1[j] = __fdiv_rn(1.0f, (float)cnt[iv[4 + j]]);
  }
  *(f32x4*)(pf + (size_t)b * N + n0) = q0;
  *(f32x4*)(pf + (size_t)b * N + n0 + 4) = q1;
}

// ---------------------------------------------------------------------------
// K2: one block per (b,c). Two-pass half-grid (64 KB slab, 2 blocks/CU,
// __launch_bounds__(1024,8) caps VGPR at 64 so 32 waves fit). lgkm-only
// barriers keep dump stores in flight across pass boundaries.
// This round: thread-contiguous point loads (n = t*8+k) -> 5 VMEM/thread
// instead of 24; nontemporal feat loads + voxout stores keep the 268 MB
// write stream from evicting idx/pf out of L2.
// ---------------------------------------------------------------------------
__global__ __launch_bounds__(1024, 8) void accum_kernel(
    const float* __restrict__ feats, const unsigned short* __restrict__ idx,
    const float* __restrict__ pf, float* __restrict__ voxout) {
  __shared__ float lds[HALF];
  const int blk = blockIdx.x;  // b*C + c
  const int c = blk & (C - 1);
  const int b = blk >> 6;
  const int t = threadIdx.x;
  const int n0 = t * PPT;

  const unsigned short* ib = idx + (size_t)b * N;
  const float* pb = pf + (size_t)b * N;
  const float* fb = feats + ((size_t)b * C + c) * N;

  // 5 vector loads: u16x8 idx, 2x f32x4 pf (cached), 2x f32x4 feat (nt --
  // single-use stream, keep L2 for idx/pf)
  const u32x4 ip = *(const u32x4*)(ib + n0);
  const f32x4 p0 = *(const f32x4*)(pb + n0);
  const f32x4 p1 = *(const f32x4*)(pb + n0 + 4);
  const f32x4 f0 = __builtin_nontemporal_load((const f32x4*)(fb + n0));
  const f32x4 f1 = __builtin_nontemporal_load((const f32x4*)(fb + n0) + 1);

  int iv[PPT];
  float fv[PPT];
#pragma unroll
  for (int j = 0; j < 4; ++j) {
    iv[2 * j] = (int)(ip[j] & 0xffffu);
    iv[2 * j + 1] = (int)(ip[j] >> 16);
  }
#pragma unroll
  for (int j = 0; j < 4; ++j) {
    fv[j] = f0[j] * p0[j];
    fv[4 + j] = f1[j] * p1[j];
  }

  f32x4* lp = (f32x4*)lds;
  const f32x4 z = {0.f, 0.f, 0.f, 0.f};

  for (int h = 0; h < 2; ++h) {
    const int lo = h * HALF;

    // zero the slab (first pass: overlaps the in-flight point loads above)
#pragma unroll
    for (int k = t; k < HALF / 4; k += T) lp[k] = z;
    lds_barrier();

    // scatter from registers (ds_add_f32; no global traffic)
#pragma unroll
    for (int k = 0; k < PPT; ++k) {
      const int loc = iv[k] - lo;
      if ((unsigned)loc < (unsigned)HALF) atomicAdd(&lds[loc], fv[k]);
    }
    lds_barrier();

    // coalesced nontemporal dump of the exclusive 64 KB slice; stores left
    // in flight across the next barrier (exclusive region, lgkm-only sync)
    f32x4* ob4 = (f32x4*)(voxout + ((size_t)b * C + c) * R3 + lo);
#pragma unroll
    for (int v = t; v < HALF / 4; v += T)
      __builtin_nontemporal_store(lp[v], ob4 + v);
    if (h == 0) lds_barrier();  // slab reused next pass
  }
}

extern "C" void kernel_launch(void* const* d_in, const int* in_sizes, int n_in,
                              void* d_out, int out_size, void* d_ws,
                              size_t ws_size, hipStream_t stream) {
  const float* feats  = (const float*)d_in[0];  // [B, C, N]
  const float* coords = (const float*)d_in[1];  // [B, 3, N]

  float* voxout = (float*)d_out;                // [B, C, R,R,R]
  float* ncout  = voxout + (size_t)B * C * R3;  // [B, 3, N]

  char* ws = (char*)d_ws;
  unsigned short* idx = (unsigned short*)(ws + IDX_OFF);
  float* pf           = (float*)(ws + PF_OFF);

  prep_kernel<<<B, 1024, 0, stream>>>(coords, ncout, idx, pf);
  accum_kernel<<<B * C, 1024, 0, stream>>>(feats, idx, pf, voxout);
}